// Round 4
// baseline (338.552 us; speedup 1.0000x reference)
//
#include <hip/hip_runtime.h>

#define G_N 200000
#define K_N 32
#define P_N 2048
#define EPSV 1e-8f
#define MINDIST 0.1f

#define PA_BLOCKS ((G_N + 255) / 256)     // 782 A blocks
#define TOTAL_BLOCKS (P_N + PA_BLOCKS)    // 2830

__device__ __forceinline__ float wave_reduce_sum(float v) {
#pragma unroll
  for (int d = 1; d < 64; d <<= 1) v += __shfl_xor(v, d, 64);
  return v;
}

// ws layout: [0, P_N)           pred row sums of R (plain store, no init needed)
//            [P_N, P_N+162)     acc: W[32] Sx[32] Sy[32] Sz[32] Q[32] cov prune
__global__ __launch_bounds__(256) void fused_main(
    const float* __restrict__ A, const float* __restrict__ x,
    const float* __restrict__ wts, const float* __restrict__ R,
    float* __restrict__ pred_sum, float* __restrict__ acc)
{
  __shared__ float smem[164];
  const int tid  = threadIdx.x;
  const int lane = tid & 63;
  const int wid  = tid >> 6;

  // Bijective remap interleaves R-stream blocks and A-compute blocks in
  // dispatch order, so every CU holds a mix at all times (997 coprime 2830).
  const int b = (int)(((long long)blockIdx.x * 997) % TOTAL_BLOCKS);

  if (b < P_N) {
    // ------- row sum of R: one block per pixel row (800 KB streamed) -------
    const int p = b;
    const float4* row = (const float4*)(R + (size_t)p * G_N);
    float s0 = 0.f, s1 = 0.f;
    int i = tid;
    for (; i + 256 < (G_N / 4); i += 512) {   // 2-way unroll for MLP
      float4 v0 = row[i];
      float4 v1 = row[i + 256];
      s0 += (v0.x + v0.y) + (v0.z + v0.w);
      s1 += (v1.x + v1.y) + (v1.z + v1.w);
    }
    for (; i < (G_N / 4); i += 256) {
      float4 v = row[i];
      s0 += (v.x + v.y) + (v.z + v.w);
    }
    float s = wave_reduce_sum(s0 + s1);
    if (lane == 0) smem[wid] = s;
    __syncthreads();
    if (tid == 0) pred_sum[p] = (smem[0] + smem[1]) + (smem[2] + smem[3]);
    return;
  }

  // ------- A-pass: one thread per gaussian -------
  const int g = (b - P_N) * 256 + tid;
  for (int i = tid; i < 162; i += 256) smem[i] = 0.f;
  __syncthreads();

  float p[K_N];
  float covp = 0.f, prw = 0.f;
  float wg = 0.f, x0 = 0.f, x1 = 0.f, x2 = 0.f, q = 0.f;

  if (g < G_N) {
    const float4* Ar = (const float4*)(A + (size_t)g * K_N);
    float a[K_N];
#pragma unroll
    for (int j = 0; j < 8; j++) {
      float4 v = Ar[j];
      a[4 * j + 0] = v.x; a[4 * j + 1] = v.y;
      a[4 * j + 2] = v.z; a[4 * j + 3] = v.w;
    }
    float m = a[0];
#pragma unroll
    for (int k = 1; k < K_N; k++) m = fmaxf(m, a[k]);
    float s = 0.f;
#pragma unroll
    for (int k = 0; k < K_N; k++) { p[k] = __expf(a[k] - m); s += p[k]; }
    const float invs = 1.f / s;

    // top-5 via branchless sorted insertion (p[k] > 0 so init 0 is safe)
    float t0 = 0.f, t1 = 0.f, t2 = 0.f, t3 = 0.f, t4 = 0.f;
#pragma unroll
    for (int k = 0; k < K_N; k++) {
      p[k] *= invs;
      float v = p[k], mx;
      mx = fmaxf(t0, v); v = fminf(t0, v); t0 = mx;
      mx = fmaxf(t1, v); v = fminf(t1, v); t1 = mx;
      mx = fmaxf(t2, v); v = fminf(t2, v); t2 = mx;
      mx = fmaxf(t3, v); v = fminf(t3, v); t3 = mx;
      mx = fmaxf(t4, v); v = fminf(t4, v); t4 = mx;
    }
    // cov pair term, stable pairwise form: sum_{i<j}(v_i - v_j)^2
    float d01 = t0 - t1, d02 = t0 - t2, d03 = t0 - t3, d04 = t0 - t4;
    float d12 = t1 - t2, d13 = t1 - t3, d14 = t1 - t4;
    float d23 = t2 - t3, d24 = t2 - t4, d34 = t3 - t4;
    covp = d01*d01 + d02*d02 + d03*d03 + d04*d04 + d12*d12
         + d13*d13 + d14*d14 + d23*d23 + d24*d24 + d34*d34;

    wg = wts[g];
    prw = fabsf(wg);
    x0 = x[3 * g + 0]; x1 = x[3 * g + 1]; x2 = x[3 * g + 2];
    q = x0 * x0 + x1 * x1 + x2 * x2;
  } else {
#pragma unroll
    for (int k = 0; k < K_N; k++) p[k] = 0.f;
  }

  // per-cluster reductions: W, S(3), Q  (wave butterfly, lane0 -> LDS)
#pragma unroll
  for (int k = 0; k < K_N; k++) {
    float c = wg * p[k];
    float v0 = c, v1 = c * x0, v2 = c * x1, v3 = c * x2, v4 = c * q;
#pragma unroll
    for (int d = 1; d < 64; d <<= 1) {
      v0 += __shfl_xor(v0, d, 64);
      v1 += __shfl_xor(v1, d, 64);
      v2 += __shfl_xor(v2, d, 64);
      v3 += __shfl_xor(v3, d, 64);
      v4 += __shfl_xor(v4, d, 64);
    }
    if (lane == 0) {
      atomicAdd(&smem[k],       v0);
      atomicAdd(&smem[32 + k],  v1);
      atomicAdd(&smem[64 + k],  v2);
      atomicAdd(&smem[96 + k],  v3);
      atomicAdd(&smem[128 + k], v4);
    }
  }
  covp = wave_reduce_sum(covp);
  prw  = wave_reduce_sum(prw);
  if (lane == 0) {
    atomicAdd(&smem[160], covp);
    atomicAdd(&smem[161], prw);
  }
  __syncthreads();
  if (tid < 162) atomicAdd(&acc[tid], smem[tid]);
}

__global__ __launch_bounds__(256) void finalize_k(
    const float* __restrict__ pred_sum, const int* __restrict__ mask,
    const float* __restrict__ acc, float* __restrict__ out)
{
  __shared__ float sred[4];
  __shared__ float cent[K_N][3];
  const int tid  = threadIdx.x;
  const int lane = tid & 63;
  const int wid  = tid >> 6;

  // ---- render BCE over P ----
  float bce = 0.f;
  for (int i = tid; i < P_N; i += 256) {
    float pred = fminf(fmaxf(pred_sum[i], 0.f), 1.f);
    float t = (float)mask[i];
    float lp = fmaxf(logf(pred), -100.f);        // logf(0) = -inf -> clamped
    float l1 = fmaxf(log1pf(-pred), -100.f);
    bce += t * lp + (1.f - t) * l1;
  }
  bce = wave_reduce_sum(bce);
  if (lane == 0) sred[wid] = bce;
  __syncthreads();
  const float render = -((sred[0] + sred[1]) + (sred[2] + sred[3])) / (float)P_N;

  // ---- dispersion + centroids (lanes 0..31 of wave 0) ----
  float disp_v = 0.f, sep_v = 0.f;
  if (tid < K_N) {
    float W  = acc[tid];
    float Sx = acc[32 + tid], Sy = acc[64 + tid], Sz = acc[96 + tid];
    float Q  = acc[128 + tid];
    float occ = W + EPSV;
    float inv = 1.f / occ;
    float cx = Sx * inv, cy = Sy * inv, cz = Sz * inv;
    cent[tid][0] = cx; cent[tid][1] = cy; cent[tid][2] = cz;
    disp_v = (Q - 2.f * (cx * Sx + cy * Sy + cz * Sz)
              + (cx * cx + cy * cy + cz * cz) * W) * inv;
  }
  __syncthreads();

  // ---- separation: lane i handles pairs (i, j>i) ----
  if (tid < K_N) {
    for (int j = tid + 1; j < K_N; j++) {
      float dx = cent[tid][0] - cent[j][0];
      float dy = cent[tid][1] - cent[j][1];
      float dz = cent[tid][2] - cent[j][2];
      float d = sqrtf(dx * dx + dy * dy + dz * dz);
      float r = fmaxf(MINDIST - d, 0.f);
      sep_v += r * r;
    }
  }
  if (tid < 64) {
    float dsum = wave_reduce_sum(disp_v);
    float ssum = wave_reduce_sum(sep_v);
    if (tid == 0) {
      float cov   = acc[160] / (float)G_N;
      float prune = acc[161];
      out[0] = render + dsum + ssum + cov + prune;
    }
  }
}

extern "C" void kernel_launch(void* const* d_in, const int* in_sizes, int n_in,
                              void* d_out, int out_size, void* d_ws, size_t ws_size,
                              hipStream_t stream) {
  const float* A    = (const float*)d_in[0];   // (G, K)
  const float* x    = (const float*)d_in[1];   // (G, 3)
  const float* wts  = (const float*)d_in[2];   // (G,)
  const float* R    = (const float*)d_in[3];   // (P, G)
  const int*   mask = (const int*)d_in[4];     // (P,)
  float* out = (float*)d_out;

  float* ws       = (float*)d_ws;
  float* pred_sum = ws;          // P_N floats (plain per-row stores)
  float* acc      = ws + P_N;    // 162 floats (atomic-accumulated, zeroed here)

  hipMemsetAsync(acc, 0, 162 * sizeof(float), stream);
  fused_main<<<TOTAL_BLOCKS, 256, 0, stream>>>(A, x, wts, R, pred_sum, acc);
  finalize_k<<<1, 256, 0, stream>>>(pred_sum, mask, acc, out);
}

// Round 5
// 317.294 us; speedup vs baseline: 1.0670x; 1.0670x over previous
//
#include <hip/hip_runtime.h>

#define G_N 200000
#define K_N 32
#define P_N 2048
#define EPSV 1e-8f
#define MINDIST 0.1f

#define PA_BLOCKS ((G_N + 255) / 256)     // 782 A blocks (blockIdx 0..781)
#define TOTAL_BLOCKS (P_N + PA_BLOCKS)    // + 2048 R blocks
#define PW_S 36                           // padded LDS row stride (floats, 16B-aligned)

__device__ __forceinline__ float wave_reduce_sum(float v) {
#pragma unroll
  for (int d = 1; d < 64; d <<= 1) v += __shfl_xor(v, d, 64);
  return v;
}

// ws layout: [0, P_N)           pred row sums of R (plain store)
//            [P_N, P_N+162)     acc: W[32] Sx[32] Sy[32] Sz[32] Q[32] cov prune
__global__ __launch_bounds__(256) void fused_main(
    const float* __restrict__ A, const float* __restrict__ x,
    const float* __restrict__ wts, const float* __restrict__ R,
    float* __restrict__ pred_sum, float* __restrict__ acc)
{
  __shared__ float smem[164];
  __shared__ float pw[256 * PW_S];   // c_k rows, transposed-read in phase 2
  __shared__ float4 xq[256];         // per-gaussian (x0,x1,x2,q)
  const int tid  = threadIdx.x;
  const int lane = tid & 63;
  const int wid  = tid >> 6;

  if (blockIdx.x >= PA_BLOCKS) {
    // ------- row sum of R: one block per pixel row (800 KB streamed) -------
    const int p = blockIdx.x - PA_BLOCKS;
    const float4* row = (const float4*)(R + (size_t)p * G_N);
    float s0 = 0.f, s1 = 0.f, s2 = 0.f, s3 = 0.f;
    int i = tid;
    for (; i + 768 < (G_N / 4); i += 1024) {   // 4 loads in flight per wave
      float4 v0 = row[i];
      float4 v1 = row[i + 256];
      float4 v2 = row[i + 512];
      float4 v3 = row[i + 768];
      s0 += (v0.x + v0.y) + (v0.z + v0.w);
      s1 += (v1.x + v1.y) + (v1.z + v1.w);
      s2 += (v2.x + v2.y) + (v2.z + v2.w);
      s3 += (v3.x + v3.y) + (v3.z + v3.w);
    }
    for (; i < (G_N / 4); i += 256) {
      float4 v = row[i];
      s0 += (v.x + v.y) + (v.z + v.w);
    }
    float s = wave_reduce_sum((s0 + s1) + (s2 + s3));
    if (lane == 0) smem[wid] = s;
    __syncthreads();
    if (tid == 0) pred_sum[p] = (smem[0] + smem[1]) + (smem[2] + smem[3]);
    return;
  }

  // ------- A-pass -------
  const int g = blockIdx.x * 256 + tid;
  if (tid < 164) smem[tid] = 0.f;

  float av[K_N];
  float covp = 0.f, prw = 0.f;
  float4 xv = make_float4(0.f, 0.f, 0.f, 0.f);

  if (g < G_N) {
    const float4* Ar = (const float4*)(A + (size_t)g * K_N);
#pragma unroll
    for (int j = 0; j < 8; j++) {
      float4 v = Ar[j];
      av[4 * j + 0] = v.x; av[4 * j + 1] = v.y;
      av[4 * j + 2] = v.z; av[4 * j + 3] = v.w;
    }
    float m = av[0];
#pragma unroll
    for (int k = 1; k < K_N; k++) m = fmaxf(m, av[k]);
    float s = 0.f;
#pragma unroll
    for (int k = 0; k < K_N; k++) { av[k] = __expf(av[k] - m); s += av[k]; }
    const float invs = 1.f / s;

    // top-5 on unnormalized exps (monotone), scale after
    float t0 = 0.f, t1 = 0.f, t2 = 0.f, t3 = 0.f, t4 = 0.f;
#pragma unroll
    for (int k = 0; k < K_N; k++) {
      float v = av[k], mx;
      mx = fmaxf(t0, v); v = fminf(t0, v); t0 = mx;
      mx = fmaxf(t1, v); v = fminf(t1, v); t1 = mx;
      mx = fmaxf(t2, v); v = fminf(t2, v); t2 = mx;
      mx = fmaxf(t3, v); v = fminf(t3, v); t3 = mx;
      mx = fmaxf(t4, v); v = fminf(t4, v); t4 = mx;
    }
    t0 *= invs; t1 *= invs; t2 *= invs; t3 *= invs; t4 *= invs;
    float d01 = t0 - t1, d02 = t0 - t2, d03 = t0 - t3, d04 = t0 - t4;
    float d12 = t1 - t2, d13 = t1 - t3, d14 = t1 - t4;
    float d23 = t2 - t3, d24 = t2 - t4, d34 = t3 - t4;
    covp = d01*d01 + d02*d02 + d03*d03 + d04*d04 + d12*d12
         + d13*d13 + d14*d14 + d23*d23 + d24*d24 + d34*d34;

    const float wg = wts[g];
    prw = fabsf(wg);
    const float x0 = x[3 * g + 0], x1 = x[3 * g + 1], x2 = x[3 * g + 2];
    xv = make_float4(x0, x1, x2, x0 * x0 + x1 * x1 + x2 * x2);

    const float cw = wg * invs;
#pragma unroll
    for (int k = 0; k < K_N; k++) av[k] *= cw;   // av[k] = c_k = wg * p_k
  } else {
#pragma unroll
    for (int k = 0; k < K_N; k++) av[k] = 0.f;
  }

  // phase 1: store c-row + (x,q) to LDS
#pragma unroll
  for (int j = 0; j < 8; j++)
    *(float4*)&pw[tid * PW_S + 4 * j] =
        make_float4(av[4*j+0], av[4*j+1], av[4*j+2], av[4*j+3]);
  xq[tid] = xv;
  __syncthreads();

  // phase 2: k-major partial sums. thread -> (cluster-quad kq, gaussian-subset sub)
  const int kq  = tid & 7;        // clusters kq*4 .. kq*4+3
  const int sub = tid >> 3;       // 32 subsets of 8 gaussians
  float4 aW = make_float4(0,0,0,0), aX = aW, aY = aW, aZ = aW, aQ = aW;
#pragma unroll
  for (int i = 0; i < 8; i++) {
    const int gg = sub * 8 + i;
    const float4 cv = *(const float4*)&pw[gg * PW_S + kq * 4];
    const float4 xg = xq[gg];     // broadcast within 8-lane group
    aW.x += cv.x;        aW.y += cv.y;        aW.z += cv.z;        aW.w += cv.w;
    aX.x += cv.x * xg.x; aX.y += cv.y * xg.x; aX.z += cv.z * xg.x; aX.w += cv.w * xg.x;
    aY.x += cv.x * xg.y; aY.y += cv.y * xg.y; aY.z += cv.z * xg.y; aY.w += cv.w * xg.y;
    aZ.x += cv.x * xg.z; aZ.y += cv.y * xg.z; aZ.z += cv.z * xg.z; aZ.w += cv.w * xg.z;
    aQ.x += cv.x * xg.w; aQ.y += cv.y * xg.w; aQ.z += cv.z * xg.w; aQ.w += cv.w * xg.w;
  }

  // phase 3: reduce the 8 subsets within each wave (3 shfl levels), then LDS atomics
#pragma unroll
  for (int d = 8; d <= 32; d <<= 1) {
    aW.x += __shfl_xor(aW.x, d, 64); aW.y += __shfl_xor(aW.y, d, 64);
    aW.z += __shfl_xor(aW.z, d, 64); aW.w += __shfl_xor(aW.w, d, 64);
    aX.x += __shfl_xor(aX.x, d, 64); aX.y += __shfl_xor(aX.y, d, 64);
    aX.z += __shfl_xor(aX.z, d, 64); aX.w += __shfl_xor(aX.w, d, 64);
    aY.x += __shfl_xor(aY.x, d, 64); aY.y += __shfl_xor(aY.y, d, 64);
    aY.z += __shfl_xor(aY.z, d, 64); aY.w += __shfl_xor(aY.w, d, 64);
    aZ.x += __shfl_xor(aZ.x, d, 64); aZ.y += __shfl_xor(aZ.y, d, 64);
    aZ.z += __shfl_xor(aZ.z, d, 64); aZ.w += __shfl_xor(aZ.w, d, 64);
    aQ.x += __shfl_xor(aQ.x, d, 64); aQ.y += __shfl_xor(aQ.y, d, 64);
    aQ.z += __shfl_xor(aQ.z, d, 64); aQ.w += __shfl_xor(aQ.w, d, 64);
  }
  if (lane < 8) {                  // lane == kq here; 4-way contention per slot
    const int k0 = lane * 4;
    atomicAdd(&smem[      k0+0], aW.x); atomicAdd(&smem[      k0+1], aW.y);
    atomicAdd(&smem[      k0+2], aW.z); atomicAdd(&smem[      k0+3], aW.w);
    atomicAdd(&smem[ 32 + k0+0], aX.x); atomicAdd(&smem[ 32 + k0+1], aX.y);
    atomicAdd(&smem[ 32 + k0+2], aX.z); atomicAdd(&smem[ 32 + k0+3], aX.w);
    atomicAdd(&smem[ 64 + k0+0], aY.x); atomicAdd(&smem[ 64 + k0+1], aY.y);
    atomicAdd(&smem[ 64 + k0+2], aY.z); atomicAdd(&smem[ 64 + k0+3], aY.w);
    atomicAdd(&smem[ 96 + k0+0], aZ.x); atomicAdd(&smem[ 96 + k0+1], aZ.y);
    atomicAdd(&smem[ 96 + k0+2], aZ.z); atomicAdd(&smem[ 96 + k0+3], aZ.w);
    atomicAdd(&smem[128 + k0+0], aQ.x); atomicAdd(&smem[128 + k0+1], aQ.y);
    atomicAdd(&smem[128 + k0+2], aQ.z); atomicAdd(&smem[128 + k0+3], aQ.w);
  }

  covp = wave_reduce_sum(covp);
  prw  = wave_reduce_sum(prw);
  if (lane == 0) {
    atomicAdd(&smem[160], covp);
    atomicAdd(&smem[161], prw);
  }
  __syncthreads();
  if (tid < 162) atomicAdd(&acc[tid], smem[tid]);
}

__global__ __launch_bounds__(256) void finalize_k(
    const float* __restrict__ pred_sum, const int* __restrict__ mask,
    const float* __restrict__ acc, float* __restrict__ out)
{
  __shared__ float sred[4];
  __shared__ float cent[K_N][3];
  const int tid  = threadIdx.x;
  const int lane = tid & 63;
  const int wid  = tid >> 6;

  // ---- render BCE over P ----
  float bce = 0.f;
  for (int i = tid; i < P_N; i += 256) {
    float pred = fminf(fmaxf(pred_sum[i], 0.f), 1.f);
    float t = (float)mask[i];
    float lp = fmaxf(logf(pred), -100.f);        // logf(0) = -inf -> clamped
    float l1 = fmaxf(log1pf(-pred), -100.f);
    bce += t * lp + (1.f - t) * l1;
  }
  bce = wave_reduce_sum(bce);
  if (lane == 0) sred[wid] = bce;
  __syncthreads();
  const float render = -((sred[0] + sred[1]) + (sred[2] + sred[3])) / (float)P_N;

  // ---- dispersion + centroids ----
  float disp_v = 0.f, sep_v = 0.f;
  if (tid < K_N) {
    float W  = acc[tid];
    float Sx = acc[32 + tid], Sy = acc[64 + tid], Sz = acc[96 + tid];
    float Q  = acc[128 + tid];
    float occ = W + EPSV;
    float inv = 1.f / occ;
    float cx = Sx * inv, cy = Sy * inv, cz = Sz * inv;
    cent[tid][0] = cx; cent[tid][1] = cy; cent[tid][2] = cz;
    disp_v = (Q - 2.f * (cx * Sx + cy * Sy + cz * Sz)
              + (cx * cx + cy * cy + cz * cz) * W) * inv;
  }
  __syncthreads();

  // ---- separation ----
  if (tid < K_N) {
    for (int j = tid + 1; j < K_N; j++) {
      float dx = cent[tid][0] - cent[j][0];
      float dy = cent[tid][1] - cent[j][1];
      float dz = cent[tid][2] - cent[j][2];
      float d = sqrtf(dx * dx + dy * dy + dz * dz);
      float r = fmaxf(MINDIST - d, 0.f);
      sep_v += r * r;
    }
  }
  if (tid < 64) {
    float dsum = wave_reduce_sum(disp_v);
    float ssum = wave_reduce_sum(sep_v);
    if (tid == 0) {
      float cov   = acc[160] / (float)G_N;
      float prune = acc[161];
      out[0] = render + dsum + ssum + cov + prune;
    }
  }
}

extern "C" void kernel_launch(void* const* d_in, const int* in_sizes, int n_in,
                              void* d_out, int out_size, void* d_ws, size_t ws_size,
                              hipStream_t stream) {
  const float* A    = (const float*)d_in[0];   // (G, K)
  const float* x    = (const float*)d_in[1];   // (G, 3)
  const float* wts  = (const float*)d_in[2];   // (G,)
  const float* R    = (const float*)d_in[3];   // (P, G)
  const int*   mask = (const int*)d_in[4];     // (P,)
  float* out = (float*)d_out;

  float* ws       = (float*)d_ws;
  float* pred_sum = ws;          // P_N floats (plain per-row stores)
  float* acc      = ws + P_N;    // 162 floats (atomic-accumulated, zeroed here)

  hipMemsetAsync(acc, 0, 162 * sizeof(float), stream);
  fused_main<<<TOTAL_BLOCKS, 256, 0, stream>>>(A, x, wts, R, pred_sum, acc);
  finalize_k<<<1, 256, 0, stream>>>(pred_sum, mask, acc, out);
}

// Round 6
// 306.452 us; speedup vs baseline: 1.1047x; 1.0354x over previous
//
#include <hip/hip_runtime.h>

#define G_N 200000
#define K_N 32
#define P_N 2048
#define EPSV 1e-8f
#define MINDIST 0.1f

#define NBLK 512
#define ROWS_PER_BLK 4                     // P_N / NBLK
#define ROW_F4 (G_N / 4)                   // 50000 float4 per row
#define REG_F4 (ROWS_PER_BLK * ROW_F4)     // 200000 float4 per block region
#define GRAB_F4 512                        // 8 wave-iters x 64 lanes
#define NGRABS ((REG_F4 + GRAB_F4 - 1) / GRAB_F4)   // 391 (last grab = 5 iters)

__device__ __forceinline__ float wave_reduce_sum(float v) {
#pragma unroll
  for (int d = 1; d < 64; d <<= 1) v += __shfl_xor(v, d, 64);
  return v;
}

// ws layout: [0, P_N)        pred row sums of R (plain store, exclusive per block)
//            [P_N, P_N+162)  acc: W[32] Sx[32] Sy[32] Sz[32] Q[32] cov prune
__global__ __launch_bounds__(256) void fused_main(
    const float* __restrict__ A, const float* __restrict__ x,
    const float* __restrict__ wts, const float* __restrict__ R,
    float* __restrict__ pred_sum, float* __restrict__ acc)
{
  __shared__ float pw[64 * 36];     // wave-0 A-transpose scratch (padded stride)
  __shared__ float4 xq[64];
  __shared__ float rowacc[ROWS_PER_BLK];
  __shared__ int ctr;

  const int tid  = threadIdx.x;
  const int lane = tid & 63;
  const int b    = blockIdx.x;

  if (tid < ROWS_PER_BLK) rowacc[tid] = 0.f;
  if (tid == 0) ctr = 0;
  __syncthreads();

  if (tid < 64) {
    // ---------- wave 0: A-pass for this block's gaussian range ----------
    const int gstart = (int)(((long long)b * G_N) / NBLK);
    const int gend   = (int)(((long long)(b + 1) * G_N) / NBLK);
    const int h = lane >> 5, k = lane & 31;
    float cW = 0.f, cX = 0.f, cY = 0.f, cZ = 0.f, cQ = 0.f;
    float covp = 0.f, prw = 0.f;

    for (int g0 = gstart; g0 < gend; g0 += 64) {
      const int g = g0 + lane;
      float av[K_N];
      float4 xv = make_float4(0.f, 0.f, 0.f, 0.f);
      if (g < gend) {
        const float4* Ar = (const float4*)(A + (size_t)g * K_N);
#pragma unroll
        for (int j = 0; j < 8; j++) {
          float4 v = Ar[j];
          av[4*j+0] = v.x; av[4*j+1] = v.y; av[4*j+2] = v.z; av[4*j+3] = v.w;
        }
        float m = av[0];
#pragma unroll
        for (int kk = 1; kk < K_N; kk++) m = fmaxf(m, av[kk]);
        float s = 0.f;
#pragma unroll
        for (int kk = 0; kk < K_N; kk++) { av[kk] = __expf(av[kk] - m); s += av[kk]; }
        const float invs = 1.f / s;

        // top-5 on unnormalized exps (monotone), scale after
        float t0 = 0.f, t1 = 0.f, t2 = 0.f, t3 = 0.f, t4 = 0.f;
#pragma unroll
        for (int kk = 0; kk < K_N; kk++) {
          float v = av[kk], mx;
          mx = fmaxf(t0, v); v = fminf(t0, v); t0 = mx;
          mx = fmaxf(t1, v); v = fminf(t1, v); t1 = mx;
          mx = fmaxf(t2, v); v = fminf(t2, v); t2 = mx;
          mx = fmaxf(t3, v); v = fminf(t3, v); t3 = mx;
          mx = fmaxf(t4, v); v = fminf(t4, v); t4 = mx;
        }
        t0 *= invs; t1 *= invs; t2 *= invs; t3 *= invs; t4 *= invs;
        float d01 = t0-t1, d02 = t0-t2, d03 = t0-t3, d04 = t0-t4;
        float d12 = t1-t2, d13 = t1-t3, d14 = t1-t4;
        float d23 = t2-t3, d24 = t2-t4, d34 = t3-t4;
        covp += d01*d01 + d02*d02 + d03*d03 + d04*d04 + d12*d12
              + d13*d13 + d14*d14 + d23*d23 + d24*d24 + d34*d34;

        const float wg = wts[g];
        prw += fabsf(wg);
        const float x0 = x[3*g+0], x1 = x[3*g+1], x2 = x[3*g+2];
        xv = make_float4(x0, x1, x2, x0*x0 + x1*x1 + x2*x2);
        const float cw = wg * invs;
#pragma unroll
        for (int kk = 0; kk < K_N; kk++) av[kk] *= cw;   // c_k = wg * p_k
      } else {
#pragma unroll
        for (int kk = 0; kk < K_N; kk++) av[kk] = 0.f;
      }

      // store c-row + xq (same-wave LDS, in-order pipe => no barrier needed)
#pragma unroll
      for (int j = 0; j < 8; j++)
        *(float4*)&pw[lane * 36 + 4*j] =
            make_float4(av[4*j+0], av[4*j+1], av[4*j+2], av[4*j+3]);
      xq[lane] = xv;

      // transposed accumulate: lane (h,k) sums its half's 32 gaussians for cluster k
#pragma unroll
      for (int i = 0; i < 32; i++) {
        const float c = pw[(h*32 + i) * 36 + k];
        const float4 xg = xq[h*32 + i];
        cW += c; cX += c*xg.x; cY += c*xg.y; cZ += c*xg.z; cQ += c*xg.w;
      }
    }

    // fold the two 32-gaussian halves, then global atomics
    cW += __shfl_xor(cW, 32, 64); cX += __shfl_xor(cX, 32, 64);
    cY += __shfl_xor(cY, 32, 64); cZ += __shfl_xor(cZ, 32, 64);
    cQ += __shfl_xor(cQ, 32, 64);
    covp = wave_reduce_sum(covp);
    prw  = wave_reduce_sum(prw);
    if (lane < 32) {
      atomicAdd(&acc[       k], cW);
      atomicAdd(&acc[ 32  + k], cX);
      atomicAdd(&acc[ 64  + k], cY);
      atomicAdd(&acc[ 96  + k], cZ);
      atomicAdd(&acc[128  + k], cQ);
    }
    if (lane == 0) { atomicAdd(&acc[160], covp); atomicAdd(&acc[161], prw); }
  }

  // ---------- all waves: sequential-region R streaming via grab counter ----------
  const float4* reg = (const float4*)R + (size_t)b * REG_F4;
  int cur_row = 0, nb = ROW_F4;
  float racc = 0.f;

  for (;;) {
    int grab;
    if (lane == 0) grab = atomicAdd(&ctr, 1);
    grab = __shfl(grab, 0, 64);
    if (grab >= NGRABS) break;
    const int base = grab * GRAB_F4;
    const int nvalid = min(8, (REG_F4 - base) >> 6);   // wave-uniform

    float4 v[8];
#pragma unroll
    for (int j = 0; j < 8; j++)
      if (j < nvalid) v[j] = reg[base + j*64 + lane];

#pragma unroll
    for (int j = 0; j < 8; j++) {
      if (j < nvalid) {
        const int q = base + j*64 + lane;
        if (q >= nb) {                       // crossed a row boundary (rare)
          atomicAdd(&rowacc[cur_row], racc);
          cur_row = q / ROW_F4;
          nb = (cur_row + 1) * ROW_F4;
          racc = 0.f;
        }
        racc += (v[j].x + v[j].y) + (v[j].z + v[j].w);
      }
    }
  }
  atomicAdd(&rowacc[cur_row], racc);
  __syncthreads();
  if (tid < ROWS_PER_BLK)
    pred_sum[b * ROWS_PER_BLK + tid] = rowacc[tid];
}

__global__ __launch_bounds__(256) void finalize_k(
    const float* __restrict__ pred_sum, const int* __restrict__ mask,
    const float* __restrict__ acc, float* __restrict__ out)
{
  __shared__ float sred[4];
  __shared__ float cent[K_N][3];
  const int tid  = threadIdx.x;
  const int lane = tid & 63;
  const int wid  = tid >> 6;

  // ---- render BCE over P ----
  float bce = 0.f;
  for (int i = tid; i < P_N; i += 256) {
    float pred = fminf(fmaxf(pred_sum[i], 0.f), 1.f);
    float t = (float)mask[i];
    float lp = fmaxf(logf(pred), -100.f);
    float l1 = fmaxf(log1pf(-pred), -100.f);
    bce += t * lp + (1.f - t) * l1;
  }
  bce = wave_reduce_sum(bce);
  if (lane == 0) sred[wid] = bce;
  __syncthreads();
  const float render = -((sred[0] + sred[1]) + (sred[2] + sred[3])) / (float)P_N;

  // ---- dispersion + centroids ----
  float disp_v = 0.f, sep_v = 0.f;
  if (tid < K_N) {
    float W  = acc[tid];
    float Sx = acc[32 + tid], Sy = acc[64 + tid], Sz = acc[96 + tid];
    float Q  = acc[128 + tid];
    float occ = W + EPSV;
    float inv = 1.f / occ;
    float cx = Sx * inv, cy = Sy * inv, cz = Sz * inv;
    cent[tid][0] = cx; cent[tid][1] = cy; cent[tid][2] = cz;
    disp_v = (Q - 2.f * (cx * Sx + cy * Sy + cz * Sz)
              + (cx * cx + cy * cy + cz * cz) * W) * inv;
  }
  __syncthreads();

  // ---- separation ----
  if (tid < K_N) {
    for (int j = tid + 1; j < K_N; j++) {
      float dx = cent[tid][0] - cent[j][0];
      float dy = cent[tid][1] - cent[j][1];
      float dz = cent[tid][2] - cent[j][2];
      float d = sqrtf(dx * dx + dy * dy + dz * dz);
      float r = fmaxf(MINDIST - d, 0.f);
      sep_v += r * r;
    }
  }
  if (tid < 64) {
    float dsum = wave_reduce_sum(disp_v);
    float ssum = wave_reduce_sum(sep_v);
    if (tid == 0) {
      float cov   = acc[160] / (float)G_N;
      float prune = acc[161];
      out[0] = render + dsum + ssum + cov + prune;
    }
  }
}

extern "C" void kernel_launch(void* const* d_in, const int* in_sizes, int n_in,
                              void* d_out, int out_size, void* d_ws, size_t ws_size,
                              hipStream_t stream) {
  const float* A    = (const float*)d_in[0];   // (G, K)
  const float* x    = (const float*)d_in[1];   // (G, 3)
  const float* wts  = (const float*)d_in[2];   // (G,)
  const float* R    = (const float*)d_in[3];   // (P, G)
  const int*   mask = (const int*)d_in[4];     // (P,)
  float* out = (float*)d_out;

  float* ws       = (float*)d_ws;
  float* pred_sum = ws;          // P_N floats (plain per-row stores)
  float* acc      = ws + P_N;    // 162 floats (atomic-accumulated, zeroed here)

  hipMemsetAsync(acc, 0, 162 * sizeof(float), stream);
  fused_main<<<NBLK, 256, 0, stream>>>(A, x, wts, R, pred_sum, acc);
  finalize_k<<<1, 256, 0, stream>>>(pred_sum, mask, acc, out);
}